// Round 23
// baseline (42.869 us; speedup 1.0000x reference)
//
#include <hip/hip_runtime.h>
#include <hip/hip_bf16.h>

#define C_IN  32
#define C_OUT 64
#define HH    64
#define WW    64
#define BREP  4   // DIAGNOSTIC (r13/r21 protocol): block replication, grid x4.
                  // Replicas run the byte-identical r22 program and store
                  // identical values -> deterministic. Lifts aeg_mfma above
                  // the 39us harness fills for rocprof top-5. Revert next round.

typedef __attribute__((ext_vector_type(8))) short short8v;
typedef __attribute__((ext_vector_type(4))) float f32x4;

static __device__ __forceinline__ unsigned short f2bf(float f) {
    unsigned u = __builtin_bit_cast(unsigned, f);
    unsigned r = (u + 0x7FFFu + ((u >> 16) & 1u)) >> 16;   // RNE
    return (unsigned short)r;
}

// x LDS geometry (r22): per ic [row:4][par:2][slot:34] + pad, slot = h+1.
// XS_ROW = 69 (odd -> stage writes <=2-way), XS_IC = 277 (==1 mod 4).
#define XS_IC   277
#define XS_ROW  69
#define XS_PAR  34

// cls stride 131 (odd -> C-stage writes <=2-way).
#define CLS_OC  131

// ---------------------------------------------------------------------------
// FUSED W~ pack (hi-only, r22 verbatim). Covering thread tt (0..255) of
// parity P: oct = tt>>6, lane = tt&63, oc = oct*16+(lane&15),
// ic = (lane>>4)*8..+7. W~_k = Ew(k)*(w_k if (P+k) odd),
// Ew(k) = prod_{j>=k,(P+j) even} w_j.
// LDS: B16[P*2304 + (k*4+oct)*64 + lane] = short8 {8 ics' bf16 hi} (16B).
// ---------------------------------------------------------------------------
template<int P>
__device__ __forceinline__ void packB(const float* __restrict__ w,
                                      short8v* __restrict__ B16, int tt)
{
    int oct  = tt >> 6;
    int lane = tt & 63;
    int oc   = oct * 16 + (lane & 15);
    int icb  = (lane >> 4) * 8;

    float wv[72];
    const f32x4* src = (const f32x4*)(w + ((size_t)oc * C_IN + icb) * 9);
    #pragma unroll
    for (int i = 0; i < 18; ++i) {
        f32x4 v = src[i];
        wv[4 * i + 0] = v.x; wv[4 * i + 1] = v.y;
        wv[4 * i + 2] = v.z; wv[4 * i + 3] = v.w;
    }

    #pragma unroll
    for (int a = 0; a < 8; ++a) {
        float Ew = 1.f;
        #pragma unroll
        for (int k = 8; k >= 0; --k) {
            float wk = wv[9 * a + k];
            if (((P + k) & 1) == 0) { Ew *= wk; wv[9 * a + k] = Ew; }
            else                    { wv[9 * a + k] = wk * Ew; }
        }
    }

    #pragma unroll
    for (int k = 0; k < 9; ++k) {
        short8v vh;
        #pragma unroll
        for (int a = 0; a < 8; ++a)
            vh[a] = (short)f2bf(wv[9 * a + k]);
        B16[P * 2304 + (k * 4 + oct) * 64 + lane] = vh;
    }
}

// ---------------------------------------------------------------------------
// GEMM body — 1-term (r22 verbatim): C = Xh * Wh.
// C mapping (m89, e2e-verified): row=(l>>4)*4+r -> position, col=l&15 -> oc.
// ---------------------------------------------------------------------------
template<int P>
__device__ __forceinline__ void aeg_gemm(
    float (&xt)[8][9], const short8v* __restrict__ Bq, f32x4 (&acc)[4], int l)
{
    #pragma unroll
    for (int a = 0; a < 8; ++a) {
        float Ox = 1.f;
        #pragma unroll
        for (int k = 8; k >= 0; --k) {
            if (((P + k) & 1) == 1) { Ox *= xt[a][k]; xt[a][k] = Ox; }
            else                    { xt[a][k] = xt[a][k] * Ox; }
        }
    }

    #pragma unroll
    for (int t = 0; t < 4; ++t) acc[t] = (f32x4){0.f, 0.f, 0.f, 0.f};

    #pragma unroll
    for (int k = 0; k < 9; ++k) {
        short8v ah;
        #pragma unroll
        for (int a = 0; a < 8; ++a) {
            __hip_bfloat16 bh = __float2bfloat16(xt[a][k]);   // RNE
            ah[a] = (short)__builtin_bit_cast(unsigned short, bh);
        }
        #pragma unroll
        for (int t = 0; t < 4; ++t) {
            short8v bh = Bq[(k * 4 + t) * 64 + l];             // W~ hi
            acc[t] = __builtin_amdgcn_mfma_f32_16x16x32_bf16(ah, bh, acc[t], 0, 0, 0);
        }
    }
}

// ---------------------------------------------------------------------------
// Main kernel, DUAL-PARITY (r22, 16.3us, passed) — byte-identical per-block
// program; only the bid decode masks replication bits.
// ---------------------------------------------------------------------------
__global__ __launch_bounds__(512, 2) void aeg_mfma(
    const float* __restrict__ x, const float* __restrict__ w,
    float* __restrict__ out)
{
    __shared__ __attribute__((aligned(16))) unsigned short Blds[36864]; // 72KB
    __shared__ float xs[C_IN * XS_IC];                                  // 35.5KB

    int bid = blockIdx.x & 255;  // DIAGNOSTIC: replicas collapse to same work
    int br  = bid & 31;          // row-block (0..31), 2 rows each
    int n   = bid >> 5;          // batch (0..7)
    int i0  = br * 2;
    int tid = threadIdx.x;

    // ---- Stage x slab: rows i0-1..i0+2, cols 0..63, all 32 ic (once) ----
    {
        const float* xn = x + (size_t)n * C_IN * HH * WW;
        #pragma unroll
        for (int c4 = 0; c4 < 4; ++c4) {
            int chunk = c4 * 512 + tid;      // 0..2047
            int ic  = chunk >> 6;
            int row = (chunk >> 4) & 3;
            int cv  = chunk & 15;
            int ii  = i0 - 1 + row;
            f32x4 v = (f32x4){0.f, 0.f, 0.f, 0.f};
            if ((unsigned)ii < 64u)
                v = *(const f32x4*)(xn + ((size_t)ic * HH + ii) * WW + cv * 4);
            float* dstp = xs + ic * XS_IC + row * XS_ROW;
            dstp[0 * XS_PAR + 2 * cv + 1] = v.x;
            dstp[1 * XS_PAR + 2 * cv + 1] = v.y;
            dstp[0 * XS_PAR + 2 * cv + 2] = v.z;
            dstp[1 * XS_PAR + 2 * cv + 2] = v.w;
        }
        if (tid < 256) {         // col-halo zeros (32ic x 4row x 2 halos)
            int ic  = tid >> 3;
            int row = (tid >> 1) & 3;
            float* dstp = xs + ic * XS_IC + row * XS_ROW;
            if (tid & 1) dstp[1 * XS_PAR + 0]  = 0.f;
            else         dstp[0 * XS_PAR + 33] = 0.f;
        }
    }

    // ---- Pack both parities' B (threads 0-255 -> P0, 256-511 -> P1) ----
    if (tid < 256) packB<0>(w, (short8v*)Blds, tid);
    else           packB<1>(w, (short8v*)Blds, tid - 256);
    __syncthreads();

    int wvv = __builtin_amdgcn_readfirstlane(tid >> 6);  // wave 0..7
    int pp  = wvv >> 2;          // parity (0..1)
    int grp = wvv & 3;           // M-group 0..3
    int l   = tid & 63;

    int qA = grp * 16 + (l & 15);
    int rb = qA >> 5;                        // wave-uniform (0 or 1)
    int iA = i0 + rb;
    int pj = (iA + pp) & 1;                  // wave-uniform col parity
    int jA = 2 * (qA & 31) + pj;
    int icb = (l >> 4) * 8;

    // ---- Tap gather from LDS (bit-identical values to r19-r22) ----
    int slotS = ((jA - 1) >> 1) + 1;
    int slotC = (jA >> 1) + 1;
    const float* xbase = xs + icb * XS_IC;

    float xt[8][9];
    #pragma unroll
    for (int a = 0; a < 8; ++a) {
        const float* pa = xbase + a * XS_IC;
        #pragma unroll
        for (int di = 0; di < 3; ++di) {
            const float* pr = pa + (rb + di) * XS_ROW;
            xt[a][di * 3 + 0] = pr[(1 - pj) * XS_PAR + slotS];
            xt[a][di * 3 + 2] = pr[(1 - pj) * XS_PAR + slotS + 1];
            xt[a][di * 3 + 1] = pr[pj * XS_PAR + slotC];
        }
    }

    const short8v* Bq = (const short8v*)Blds + pp * 2304;
    f32x4 acc[4];
    if (pp == 0) aeg_gemm<0>(xt, Bq, acc, l);
    else         aeg_gemm<1>(xt, Bq, acc, l);

    // ---- Epilogue: assemble FULL tile (both parities) in LDS, store ----
    __syncthreads();                       // all B reads done
    float* cls = (float*)Blds;             // cls[oc*131 + pp*64 + q], 33.5KB

    {
        int colc = l & 15;
        int rgrp = l >> 4;
        #pragma unroll
        for (int t = 0; t < 4; ++t) {
            int oc = t * 16 + colc;
            #pragma unroll
            for (int r = 0; r < 4; ++r) {
                int q = grp * 16 + rgrp * 4 + r;   // position 0..63 in parity
                cls[oc * CLS_OC + pp * 64 + q] = acc[t][r];
            }
        }
    }
    __syncthreads();

    // Full-line write-out: 8192 values, lane -> q within (oc, parity) stripe.
    #pragma unroll
    for (int v = 0; v < 16; ++v) {
        int flat = v * 512 + tid;          // 0..8191
        int oc   = flat >> 7;
        int rr   = flat & 127;
        int pq   = rr >> 6;                // parity
        int q    = rr & 63;
        int i    = i0 + (q >> 5);
        int j    = 2 * (q & 31) + ((i + pq) & 1);
        out[(((size_t)n * C_OUT + oc) * HH + i) * WW + j] = cls[oc * CLS_OC + pq * 64 + q];
    }
}

extern "C" void kernel_launch(void* const* d_in, const int* in_sizes, int n_in,
                              void* d_out, int out_size, void* d_ws, size_t ws_size,
                              hipStream_t stream) {
    const float* x = (const float*)d_in[0];
    const float* w = (const float*)d_in[1];
    float* out = (float*)d_out;
    (void)d_ws; (void)ws_size;

    aeg_mfma<<<256 * BREP, 512, 0, stream>>>(x, w, out);
}

// Round 24
// 16.159 us; speedup vs baseline: 2.6529x; 2.6529x over previous
//
#include <hip/hip_runtime.h>
#include <hip/hip_bf16.h>

#define C_IN  32
#define C_OUT 64
#define HH    64
#define WW    64

typedef __attribute__((ext_vector_type(8))) short short8v;
typedef __attribute__((ext_vector_type(4))) float f32x4;

static __device__ __forceinline__ short bf_hi(float f) {
    // Native RNE cast (compiler emits v_cvt_pk_bf16_f32 pairs).
    // Verified bit-identical to the manual round-and-shift in r14 (absmax
    // unchanged when gemm switched); r24 applies the same to packB.
    __hip_bfloat16 b = __float2bfloat16(f);
    return (short)__builtin_bit_cast(unsigned short, b);
}

// x LDS geometry (r22): per ic [row:4][par:2][slot:34] + pad, slot = h+1.
// XS_ROW = 69 (odd), XS_IC = 277 (==1 mod 4 -> 8-ic groups at bank offsets
// {0,8,16,24}; 16-lane stride-1 reads <=2-way = free).
#define XS_IC   277
#define XS_ROW  69
#define XS_PAR  34

// cls stride 131 (odd).
#define CLS_OC  131

// ---------------------------------------------------------------------------
// FUSED W~ pack (hi-only). r24: native bf16 casts (was manual f2bf — ~220
// VALU/thread of bit-twiddle deleted from the longest serial phase).
// Covering thread tt (0..255) of parity P: oct = tt>>6, lane = tt&63,
// oc = oct*16+(lane&15), ic = (lane>>4)*8..+7.
// W~_k = Ew(k)*(w_k if (P+k) odd), Ew(k) = prod_{j>=k,(P+j) even} w_j.
// LDS: B16[P*2304 + (k*4+oct)*64 + lane] = short8 {8 ics' bf16 hi} (16B).
// ---------------------------------------------------------------------------
template<int P>
__device__ __forceinline__ void packB(const float* __restrict__ w,
                                      short8v* __restrict__ B16, int tt)
{
    int oct  = tt >> 6;
    int lane = tt & 63;
    int oc   = oct * 16 + (lane & 15);
    int icb  = (lane >> 4) * 8;

    float wv[72];
    const f32x4* src = (const f32x4*)(w + ((size_t)oc * C_IN + icb) * 9);
    #pragma unroll
    for (int i = 0; i < 18; ++i) {
        f32x4 v = src[i];
        wv[4 * i + 0] = v.x; wv[4 * i + 1] = v.y;
        wv[4 * i + 2] = v.z; wv[4 * i + 3] = v.w;
    }

    #pragma unroll
    for (int a = 0; a < 8; ++a) {
        float Ew = 1.f;
        #pragma unroll
        for (int k = 8; k >= 0; --k) {
            float wk = wv[9 * a + k];
            if (((P + k) & 1) == 0) { Ew *= wk; wv[9 * a + k] = Ew; }
            else                    { wv[9 * a + k] = wk * Ew; }
        }
    }

    #pragma unroll
    for (int k = 0; k < 9; ++k) {
        short8v vh;
        #pragma unroll
        for (int a = 0; a < 8; ++a)
            vh[a] = bf_hi(wv[9 * a + k]);
        B16[P * 2304 + (k * 4 + oct) * 64 + lane] = vh;
    }
}

// ---------------------------------------------------------------------------
// GEMM body — 1-term (r22 verbatim): C = Xh * Wh.
// C mapping (m89, e2e-verified): row=(l>>4)*4+r -> position, col=l&15 -> oc.
// ---------------------------------------------------------------------------
template<int P>
__device__ __forceinline__ void aeg_gemm(
    float (&xt)[8][9], const short8v* __restrict__ Bq, f32x4 (&acc)[4], int l)
{
    // X~: suffix products of odd-step x's; even steps multiply own x.
    #pragma unroll
    for (int a = 0; a < 8; ++a) {
        float Ox = 1.f;
        #pragma unroll
        for (int k = 8; k >= 0; --k) {
            if (((P + k) & 1) == 1) { Ox *= xt[a][k]; xt[a][k] = Ox; }
            else                    { xt[a][k] = xt[a][k] * Ox; }
        }
    }

    #pragma unroll
    for (int t = 0; t < 4; ++t) acc[t] = (f32x4){0.f, 0.f, 0.f, 0.f};

    #pragma unroll
    for (int k = 0; k < 9; ++k) {
        short8v ah;
        #pragma unroll
        for (int a = 0; a < 8; ++a)
            ah[a] = bf_hi(xt[a][k]);
        #pragma unroll
        for (int t = 0; t < 4; ++t) {
            short8v bh = Bq[(k * 4 + t) * 64 + l];             // W~ hi
            acc[t] = __builtin_amdgcn_mfma_f32_16x16x32_bf16(ah, bh, acc[t], 0, 0, 0);
        }
    }
}

// ---------------------------------------------------------------------------
// Main kernel, DUAL-PARITY (r22 structure, 16.3us): block = 1 n x 2 rows x
// 64 cols x both parities, 512 thr = 8 waves (0-3 P0, 4-7 P1), grid 256 =
// 1 block/CU. x-slab staged once; full-tile LDS epilogue. r24 delta: native
// bf16 casts in packB only.
// ---------------------------------------------------------------------------
__global__ __launch_bounds__(512, 2) void aeg_mfma(
    const float* __restrict__ x, const float* __restrict__ w,
    float* __restrict__ out)
{
    __shared__ __attribute__((aligned(16))) unsigned short Blds[36864]; // 72KB
    __shared__ float xs[C_IN * XS_IC];                                  // 35.5KB

    int bid = blockIdx.x;
    int br  = bid & 31;          // row-block (0..31), 2 rows each
    int n   = bid >> 5;          // batch (0..7)
    int i0  = br * 2;
    int tid = threadIdx.x;

    // ---- Stage x slab: rows i0-1..i0+2, cols 0..63, all 32 ic (once) ----
    {
        const float* xn = x + (size_t)n * C_IN * HH * WW;
        #pragma unroll
        for (int c4 = 0; c4 < 4; ++c4) {
            int chunk = c4 * 512 + tid;      // 0..2047
            int ic  = chunk >> 6;
            int row = (chunk >> 4) & 3;
            int cv  = chunk & 15;
            int ii  = i0 - 1 + row;
            f32x4 v = (f32x4){0.f, 0.f, 0.f, 0.f};
            if ((unsigned)ii < 64u)
                v = *(const f32x4*)(xn + ((size_t)ic * HH + ii) * WW + cv * 4);
            float* dstp = xs + ic * XS_IC + row * XS_ROW;
            dstp[0 * XS_PAR + 2 * cv + 1] = v.x;
            dstp[1 * XS_PAR + 2 * cv + 1] = v.y;
            dstp[0 * XS_PAR + 2 * cv + 2] = v.z;
            dstp[1 * XS_PAR + 2 * cv + 2] = v.w;
        }
        if (tid < 256) {         // col-halo zeros (32ic x 4row x 2 halos)
            int ic  = tid >> 3;
            int row = (tid >> 1) & 3;
            float* dstp = xs + ic * XS_IC + row * XS_ROW;
            if (tid & 1) dstp[1 * XS_PAR + 0]  = 0.f;
            else         dstp[0 * XS_PAR + 33] = 0.f;
        }
    }

    // ---- Pack both parities' B (threads 0-255 -> P0, 256-511 -> P1) ----
    if (tid < 256) packB<0>(w, (short8v*)Blds, tid);
    else           packB<1>(w, (short8v*)Blds, tid - 256);
    __syncthreads();

    int wvv = __builtin_amdgcn_readfirstlane(tid >> 6);  // wave 0..7
    int pp  = wvv >> 2;          // parity (0..1)
    int grp = wvv & 3;           // M-group 0..3
    int l   = tid & 63;

    int qA = grp * 16 + (l & 15);
    int rb = qA >> 5;                        // wave-uniform (0 or 1)
    int iA = i0 + rb;
    int pj = (iA + pp) & 1;                  // wave-uniform col parity
    int jA = 2 * (qA & 31) + pj;
    int icb = (l >> 4) * 8;

    // ---- Tap gather from LDS (bit-identical values to r19-r23) ----
    int slotS = ((jA - 1) >> 1) + 1;
    int slotC = (jA >> 1) + 1;
    const float* xbase = xs + icb * XS_IC;

    float xt[8][9];
    #pragma unroll
    for (int a = 0; a < 8; ++a) {
        const float* pa = xbase + a * XS_IC;
        #pragma unroll
        for (int di = 0; di < 3; ++di) {
            const float* pr = pa + (rb + di) * XS_ROW;
            xt[a][di * 3 + 0] = pr[(1 - pj) * XS_PAR + slotS];
            xt[a][di * 3 + 2] = pr[(1 - pj) * XS_PAR + slotS + 1];
            xt[a][di * 3 + 1] = pr[pj * XS_PAR + slotC];
        }
    }

    const short8v* Bq = (const short8v*)Blds + pp * 2304;
    f32x4 acc[4];
    if (pp == 0) aeg_gemm<0>(xt, Bq, acc, l);
    else         aeg_gemm<1>(xt, Bq, acc, l);

    // ---- Epilogue: assemble FULL tile (both parities) in LDS, store ----
    __syncthreads();                       // all B reads done
    float* cls = (float*)Blds;             // cls[oc*131 + pp*64 + q], 33.5KB

    {
        int colc = l & 15;
        int rgrp = l >> 4;
        #pragma unroll
        for (int t = 0; t < 4; ++t) {
            int oc = t * 16 + colc;
            #pragma unroll
            for (int r = 0; r < 4; ++r) {
                int q = grp * 16 + rgrp * 4 + r;   // position 0..63 in parity
                cls[oc * CLS_OC + pp * 64 + q] = acc[t][r];
            }
        }
    }
    __syncthreads();

    // Full-line write-out: 8192 values, lane -> q within (oc, parity) stripe.
    #pragma unroll
    for (int v = 0; v < 16; ++v) {
        int flat = v * 512 + tid;          // 0..8191
        int oc   = flat >> 7;
        int rr   = flat & 127;
        int pq   = rr >> 6;                // parity
        int q    = rr & 63;
        int i    = i0 + (q >> 5);
        int j    = 2 * (q & 31) + ((i + pq) & 1);
        out[(((size_t)n * C_OUT + oc) * HH + i) * WW + j] = cls[oc * CLS_OC + pq * 64 + q];
    }
}

extern "C" void kernel_launch(void* const* d_in, const int* in_sizes, int n_in,
                              void* d_out, int out_size, void* d_ws, size_t ws_size,
                              hipStream_t stream) {
    const float* x = (const float*)d_in[0];
    const float* w = (const float*)d_in[1];
    float* out = (float*)d_out;
    (void)d_ws; (void)ws_size;

    aeg_mfma<<<256, 512, 0, stream>>>(x, w, out);
}

// Round 25
// 15.522 us; speedup vs baseline: 2.7618x; 1.0411x over previous
//
#include <hip/hip_runtime.h>
#include <hip/hip_bf16.h>

#define C_IN  32
#define C_OUT 64
#define HH    64
#define WW    64

typedef __attribute__((ext_vector_type(8))) short short8v;
typedef __attribute__((ext_vector_type(4))) float f32x4;

static __device__ __forceinline__ short bf_hi(float f) {
    __hip_bfloat16 b = __float2bfloat16(f);   // native RNE cast (cvt_pk pairs)
    return (short)__builtin_bit_cast(unsigned short, b);
}

// x LDS geometry (r22): per ic [row:4][par:2][slot:34] + pad, slot = h+1.
// XS_ROW = 69 (odd), XS_IC = 277 (==1 mod 4 -> 8-ic groups at bank offsets
// {0,8,16,24}; 16-lane stride-1 reads <=2-way = free).
#define XS_IC   277
#define XS_ROW  69
#define XS_PAR  34

// cls stride 131 (odd; lives in the xs region after taps are consumed).
#define CLS_OC  131

// ---------------------------------------------------------------------------
// FUSED W~ pack (hi-only, r24 verbatim). Covering thread tt (0..255) of
// parity P: oct = tt>>6, lane = tt&63, oc = oct*16+(lane&15),
// ic = (lane>>4)*8..+7. W~_k = Ew(k)*(w_k if (P+k) odd),
// Ew(k) = prod_{j>=k,(P+j) even} w_j.
// LDS: B16[P*2304 + (k*4+oct)*64 + lane] = short8 {8 ics' bf16 hi} (16B).
// ---------------------------------------------------------------------------
template<int P>
__device__ __forceinline__ void packB(const float* __restrict__ w,
                                      short8v* __restrict__ B16, int tt)
{
    int oct  = tt >> 6;
    int lane = tt & 63;
    int oc   = oct * 16 + (lane & 15);
    int icb  = (lane >> 4) * 8;

    float wv[72];
    const f32x4* src = (const f32x4*)(w + ((size_t)oc * C_IN + icb) * 9);
    #pragma unroll
    for (int i = 0; i < 18; ++i) {
        f32x4 v = src[i];
        wv[4 * i + 0] = v.x; wv[4 * i + 1] = v.y;
        wv[4 * i + 2] = v.z; wv[4 * i + 3] = v.w;
    }

    #pragma unroll
    for (int a = 0; a < 8; ++a) {
        float Ew = 1.f;
        #pragma unroll
        for (int k = 8; k >= 0; --k) {
            float wk = wv[9 * a + k];
            if (((P + k) & 1) == 0) { Ew *= wk; wv[9 * a + k] = Ew; }
            else                    { wv[9 * a + k] = wk * Ew; }
        }
    }

    #pragma unroll
    for (int k = 0; k < 9; ++k) {
        short8v vh;
        #pragma unroll
        for (int a = 0; a < 8; ++a)
            vh[a] = bf_hi(wv[9 * a + k]);
        B16[P * 2304 + (k * 4 + oct) * 64 + lane] = vh;
    }
}

// ---------------------------------------------------------------------------
// GEMM body — 1-term (r22/r24 verbatim): C = Xh * Wh.
// C mapping (m89, e2e-verified): row=(l>>4)*4+r -> position, col=l&15 -> oc.
// ---------------------------------------------------------------------------
template<int P>
__device__ __forceinline__ void aeg_gemm(
    float (&xt)[8][9], const short8v* __restrict__ Bq, f32x4 (&acc)[4], int l)
{
    #pragma unroll
    for (int a = 0; a < 8; ++a) {
        float Ox = 1.f;
        #pragma unroll
        for (int k = 8; k >= 0; --k) {
            if (((P + k) & 1) == 1) { Ox *= xt[a][k]; xt[a][k] = Ox; }
            else                    { xt[a][k] = xt[a][k] * Ox; }
        }
    }

    #pragma unroll
    for (int t = 0; t < 4; ++t) acc[t] = (f32x4){0.f, 0.f, 0.f, 0.f};

    #pragma unroll
    for (int k = 0; k < 9; ++k) {
        short8v ah;
        #pragma unroll
        for (int a = 0; a < 8; ++a)
            ah[a] = bf_hi(xt[a][k]);
        #pragma unroll
        for (int t = 0; t < 4; ++t) {
            short8v bh = Bq[(k * 4 + t) * 64 + l];             // W~ hi
            acc[t] = __builtin_amdgcn_mfma_f32_16x16x32_bf16(ah, bh, acc[t], 0, 0, 0);
        }
    }
}

// ---------------------------------------------------------------------------
// Main kernel, DUAL-PARITY (r24 structure). r25 deltas (epilogue only):
// (1) C staged into the xs region (dead after tap-gather) -> the full-block
//     barrier moves from post-GEMM to post-tap; waves stage C as they
//     finish instead of all waiting for the slowest GEMM.
// (2) Write-out assembles f32x4 (4 cls b32 reads, 2-way banked) and emits
//     4 coalesced dwordx4 stores/thread (was 16 scalar dwords).
// ---------------------------------------------------------------------------
__global__ __launch_bounds__(512, 2) void aeg_mfma(
    const float* __restrict__ x, const float* __restrict__ w,
    float* __restrict__ out)
{
    __shared__ __attribute__((aligned(16))) unsigned short Blds[36864]; // 72KB
    __shared__ float xs[C_IN * XS_IC];                                  // 35.5KB (8864 f)

    int bid = blockIdx.x;
    int br  = bid & 31;          // row-block (0..31), 2 rows each
    int n   = bid >> 5;          // batch (0..7)
    int i0  = br * 2;
    int tid = threadIdx.x;

    // ---- Stage x slab: rows i0-1..i0+2, cols 0..63, all 32 ic (once) ----
    {
        const float* xn = x + (size_t)n * C_IN * HH * WW;
        #pragma unroll
        for (int c4 = 0; c4 < 4; ++c4) {
            int chunk = c4 * 512 + tid;      // 0..2047
            int ic  = chunk >> 6;
            int row = (chunk >> 4) & 3;
            int cv  = chunk & 15;
            int ii  = i0 - 1 + row;
            f32x4 v = (f32x4){0.f, 0.f, 0.f, 0.f};
            if ((unsigned)ii < 64u)
                v = *(const f32x4*)(xn + ((size_t)ic * HH + ii) * WW + cv * 4);
            float* dstp = xs + ic * XS_IC + row * XS_ROW;
            dstp[0 * XS_PAR + 2 * cv + 1] = v.x;
            dstp[1 * XS_PAR + 2 * cv + 1] = v.y;
            dstp[0 * XS_PAR + 2 * cv + 2] = v.z;
            dstp[1 * XS_PAR + 2 * cv + 2] = v.w;
        }
        if (tid < 256) {         // col-halo zeros (32ic x 4row x 2 halos)
            int ic  = tid >> 3;
            int row = (tid >> 1) & 3;
            float* dstp = xs + ic * XS_IC + row * XS_ROW;
            if (tid & 1) dstp[1 * XS_PAR + 0]  = 0.f;
            else         dstp[0 * XS_PAR + 33] = 0.f;
        }
    }

    // ---- Pack both parities' B (threads 0-255 -> P0, 256-511 -> P1) ----
    if (tid < 256) packB<0>(w, (short8v*)Blds, tid);
    else           packB<1>(w, (short8v*)Blds, tid - 256);
    __syncthreads();

    int wvv = __builtin_amdgcn_readfirstlane(tid >> 6);  // wave 0..7
    int pp  = wvv >> 2;          // parity (0..1)
    int grp = wvv & 3;           // M-group 0..3
    int l   = tid & 63;

    int qA = grp * 16 + (l & 15);
    int rb = qA >> 5;                        // wave-uniform (0 or 1)
    int iA = i0 + rb;
    int pj = (iA + pp) & 1;                  // wave-uniform col parity
    int jA = 2 * (qA & 31) + pj;
    int icb = (l >> 4) * 8;

    // ---- Tap gather from LDS (bit-identical values to r19-r24) ----
    int slotS = ((jA - 1) >> 1) + 1;
    int slotC = (jA >> 1) + 1;
    const float* xbase = xs + icb * XS_IC;

    float xt[8][9];
    #pragma unroll
    for (int a = 0; a < 8; ++a) {
        const float* pa = xbase + a * XS_IC;
        #pragma unroll
        for (int di = 0; di < 3; ++di) {
            const float* pr = pa + (rb + di) * XS_ROW;
            xt[a][di * 3 + 0] = pr[(1 - pj) * XS_PAR + slotS];
            xt[a][di * 3 + 2] = pr[(1 - pj) * XS_PAR + slotS + 1];
            xt[a][di * 3 + 1] = pr[pj * XS_PAR + slotC];
        }
    }
    __syncthreads();             // all taps read chip-wide; xs reusable for C

    const short8v* Bq = (const short8v*)Blds + pp * 2304;
    f32x4 acc[4];
    if (pp == 0) aeg_gemm<0>(xt, Bq, acc, l);
    else         aeg_gemm<1>(xt, Bq, acc, l);

    // ---- C-stage into xs (Blds untouched -> no post-GEMM hazard) ----
    float* cls = xs;             // cls[oc*131 + pp*64 + q], 33.5KB <= 35.5KB
    {
        int colc = l & 15;
        int rgrp = l >> 4;
        #pragma unroll
        for (int t = 0; t < 4; ++t) {
            int oc = t * 16 + colc;
            #pragma unroll
            for (int r = 0; r < 4; ++r) {
                int q = grp * 16 + rgrp * 4 + r;   // position 0..63 in parity
                cls[oc * CLS_OC + pp * 64 + q] = acc[t][r];
            }
        }
    }
    __syncthreads();

    // ---- Write-out: assemble x4 from both parities, 4 dwordx4/thread ----
    #pragma unroll
    for (int v = 0; v < 4; ++v) {
        int g   = v * 512 + tid;           // 0..2047 (x4 groups)
        int oc  = g >> 5;
        int rem = g & 31;
        int il  = rem >> 4;
        int j0  = (rem & 15) * 4;
        int i   = i0 + il;
        f32x4 vv;
        #pragma unroll
        for (int d = 0; d < 4; ++d) {
            int j  = j0 + d;
            int pq = (i + j) & 1;          // parity owning column j of row i
            int q  = (il << 5) | (j >> 1);
            vv[d] = cls[oc * CLS_OC + pq * 64 + q];
        }
        *(f32x4*)(out + (((size_t)n * C_OUT + oc) * HH + i) * WW + j0) = vv;
    }
}

extern "C" void kernel_launch(void* const* d_in, const int* in_sizes, int n_in,
                              void* d_out, int out_size, void* d_ws, size_t ws_size,
                              hipStream_t stream) {
    const float* x = (const float*)d_in[0];
    const float* w = (const float*)d_in[1];
    float* out = (float*)d_out;
    (void)d_ws; (void)ws_size;

    aeg_mfma<<<256, 512, 0, stream>>>(x, w, out);
}

// Round 26
// 15.340 us; speedup vs baseline: 2.7946x; 1.0119x over previous
//
#include <hip/hip_runtime.h>
#include <hip/hip_bf16.h>

#define C_IN  32
#define C_OUT 64
#define HH    64
#define WW    64

typedef __attribute__((ext_vector_type(8))) short short8v;
typedef __attribute__((ext_vector_type(4))) float f32x4;

static __device__ __forceinline__ short bf_hi(float f) {
    __hip_bfloat16 b = __float2bfloat16(f);   // native RNE cast (cvt_pk pairs)
    return (short)__builtin_bit_cast(unsigned short, b);
}

// x LDS geometry (r22): per ic [row:4][par:2][slot:34] + pad, slot = h+1.
// XS_ROW = 69 (odd), XS_IC = 277 (==1 mod 4 -> 8-ic groups at bank offsets
// {0,8,16,24}; 16-lane stride-1 reads <=2-way = free).
#define XS_IC   277
#define XS_ROW  69
#define XS_PAR  34

// cls stride 131 (odd). r26: cls is its OWN LDS region (not aliasing xs) ->
// the tap->GEMM barrier is gone; only 2 barriers remain in the kernel.
#define CLS_OC  131

// ---------------------------------------------------------------------------
// FUSED W~ pack (hi-only, r24 verbatim). Covering thread tt (0..255) of
// parity P: oct = tt>>6, lane = tt&63, oc = oct*16+(lane&15),
// ic = (lane>>4)*8..+7. W~_k = Ew(k)*(w_k if (P+k) odd),
// Ew(k) = prod_{j>=k,(P+j) even} w_j.
// LDS: B16[P*2304 + (k*4+oct)*64 + lane] = short8 {8 ics' bf16 hi} (16B).
// ---------------------------------------------------------------------------
template<int P>
__device__ __forceinline__ void packB(const float* __restrict__ w,
                                      short8v* __restrict__ B16, int tt)
{
    int oct  = tt >> 6;
    int lane = tt & 63;
    int oc   = oct * 16 + (lane & 15);
    int icb  = (lane >> 4) * 8;

    float wv[72];
    const f32x4* src = (const f32x4*)(w + ((size_t)oc * C_IN + icb) * 9);
    #pragma unroll
    for (int i = 0; i < 18; ++i) {
        f32x4 v = src[i];
        wv[4 * i + 0] = v.x; wv[4 * i + 1] = v.y;
        wv[4 * i + 2] = v.z; wv[4 * i + 3] = v.w;
    }

    #pragma unroll
    for (int a = 0; a < 8; ++a) {
        float Ew = 1.f;
        #pragma unroll
        for (int k = 8; k >= 0; --k) {
            float wk = wv[9 * a + k];
            if (((P + k) & 1) == 0) { Ew *= wk; wv[9 * a + k] = Ew; }
            else                    { wv[9 * a + k] = wk * Ew; }
        }
    }

    #pragma unroll
    for (int k = 0; k < 9; ++k) {
        short8v vh;
        #pragma unroll
        for (int a = 0; a < 8; ++a)
            vh[a] = bf_hi(wv[9 * a + k]);
        B16[P * 2304 + (k * 4 + oct) * 64 + lane] = vh;
    }
}

// ---------------------------------------------------------------------------
// GEMM body — 1-term (r22/r24 verbatim): C = Xh * Wh.
// C mapping (m89, e2e-verified): row=(l>>4)*4+r -> position, col=l&15 -> oc.
// ---------------------------------------------------------------------------
template<int P>
__device__ __forceinline__ void aeg_gemm(
    float (&xt)[8][9], const short8v* __restrict__ Bq, f32x4 (&acc)[4], int l)
{
    #pragma unroll
    for (int a = 0; a < 8; ++a) {
        float Ox = 1.f;
        #pragma unroll
        for (int k = 8; k >= 0; --k) {
            if (((P + k) & 1) == 1) { Ox *= xt[a][k]; xt[a][k] = Ox; }
            else                    { xt[a][k] = xt[a][k] * Ox; }
        }
    }

    #pragma unroll
    for (int t = 0; t < 4; ++t) acc[t] = (f32x4){0.f, 0.f, 0.f, 0.f};

    #pragma unroll
    for (int k = 0; k < 9; ++k) {
        short8v ah;
        #pragma unroll
        for (int a = 0; a < 8; ++a)
            ah[a] = bf_hi(xt[a][k]);
        #pragma unroll
        for (int t = 0; t < 4; ++t) {
            short8v bh = Bq[(k * 4 + t) * 64 + l];             // W~ hi
            acc[t] = __builtin_amdgcn_mfma_f32_16x16x32_bf16(ah, bh, acc[t], 0, 0, 0);
        }
    }
}

// ---------------------------------------------------------------------------
// Main kernel, DUAL-PARITY (r25 structure). r26 delta: dedicated cls region
// (139.4KB total LDS, still 1 block/CU) -> tap->GEMM barrier REMOVED. Waves
// flow stage -> bar -> tap -> gemm -> C-stage -> bar -> write-out; fast
// waves' GEMM overlaps slow waves' tap reads.
// ---------------------------------------------------------------------------
__global__ __launch_bounds__(512, 2) void aeg_mfma(
    const float* __restrict__ x, const float* __restrict__ w,
    float* __restrict__ out)
{
    __shared__ __attribute__((aligned(16))) unsigned short Blds[36864]; // 72KB
    __shared__ float xs[C_IN * XS_IC];                                  // 34.6KB
    __shared__ float cls[C_OUT * CLS_OC];                               // 32.8KB

    int bid = blockIdx.x;
    int br  = bid & 31;          // row-block (0..31), 2 rows each
    int n   = bid >> 5;          // batch (0..7)
    int i0  = br * 2;
    int tid = threadIdx.x;

    // ---- Stage x slab: rows i0-1..i0+2, cols 0..63, all 32 ic (once) ----
    {
        const float* xn = x + (size_t)n * C_IN * HH * WW;
        #pragma unroll
        for (int c4 = 0; c4 < 4; ++c4) {
            int chunk = c4 * 512 + tid;      // 0..2047
            int ic  = chunk >> 6;
            int row = (chunk >> 4) & 3;
            int cv  = chunk & 15;
            int ii  = i0 - 1 + row;
            f32x4 v = (f32x4){0.f, 0.f, 0.f, 0.f};
            if ((unsigned)ii < 64u)
                v = *(const f32x4*)(xn + ((size_t)ic * HH + ii) * WW + cv * 4);
            float* dstp = xs + ic * XS_IC + row * XS_ROW;
            dstp[0 * XS_PAR + 2 * cv + 1] = v.x;
            dstp[1 * XS_PAR + 2 * cv + 1] = v.y;
            dstp[0 * XS_PAR + 2 * cv + 2] = v.z;
            dstp[1 * XS_PAR + 2 * cv + 2] = v.w;
        }
        if (tid < 256) {         // col-halo zeros (32ic x 4row x 2 halos)
            int ic  = tid >> 3;
            int row = (tid >> 1) & 3;
            float* dstp = xs + ic * XS_IC + row * XS_ROW;
            if (tid & 1) dstp[1 * XS_PAR + 0]  = 0.f;
            else         dstp[0 * XS_PAR + 33] = 0.f;
        }
    }

    // ---- Pack both parities' B (threads 0-255 -> P0, 256-511 -> P1) ----
    if (tid < 256) packB<0>(w, (short8v*)Blds, tid);
    else           packB<1>(w, (short8v*)Blds, tid - 256);
    __syncthreads();             // barrier 1: xs + B ready

    int wvv = __builtin_amdgcn_readfirstlane(tid >> 6);  // wave 0..7
    int pp  = wvv >> 2;          // parity (0..1)
    int grp = wvv & 3;           // M-group 0..3
    int l   = tid & 63;

    int qA = grp * 16 + (l & 15);
    int rb = qA >> 5;                        // wave-uniform (0 or 1)
    int iA = i0 + rb;
    int pj = (iA + pp) & 1;                  // wave-uniform col parity
    int jA = 2 * (qA & 31) + pj;
    int icb = (l >> 4) * 8;

    // ---- Tap gather from LDS (bit-identical values to r19-r25) ----
    int slotS = ((jA - 1) >> 1) + 1;
    int slotC = (jA >> 1) + 1;
    const float* xbase = xs + icb * XS_IC;

    float xt[8][9];
    #pragma unroll
    for (int a = 0; a < 8; ++a) {
        const float* pa = xbase + a * XS_IC;
        #pragma unroll
        for (int di = 0; di < 3; ++di) {
            const float* pr = pa + (rb + di) * XS_ROW;
            xt[a][di * 3 + 0] = pr[(1 - pj) * XS_PAR + slotS];
            xt[a][di * 3 + 2] = pr[(1 - pj) * XS_PAR + slotS + 1];
            xt[a][di * 3 + 1] = pr[pj * XS_PAR + slotC];
        }
    }
    // (no barrier — cls is a dedicated region, taps/GEMM/C-stage can overlap
    //  across waves)

    const short8v* Bq = (const short8v*)Blds + pp * 2304;
    f32x4 acc[4];
    if (pp == 0) aeg_gemm<0>(xt, Bq, acc, l);
    else         aeg_gemm<1>(xt, Bq, acc, l);

    // ---- C-stage into dedicated cls ----
    {
        int colc = l & 15;
        int rgrp = l >> 4;
        #pragma unroll
        for (int t = 0; t < 4; ++t) {
            int oc = t * 16 + colc;
            #pragma unroll
            for (int r = 0; r < 4; ++r) {
                int q = grp * 16 + rgrp * 4 + r;   // position 0..63 in parity
                cls[oc * CLS_OC + pp * 64 + q] = acc[t][r];
            }
        }
    }
    __syncthreads();             // barrier 2: full C tile staged

    // ---- Write-out: assemble x4 from both parities, 4 dwordx4/thread ----
    #pragma unroll
    for (int v = 0; v < 4; ++v) {
        int g   = v * 512 + tid;           // 0..2047 (x4 groups)
        int oc  = g >> 5;
        int rem = g & 31;
        int il  = rem >> 4;
        int j0  = (rem & 15) * 4;
        int i   = i0 + il;
        f32x4 vv;
        #pragma unroll
        for (int d = 0; d < 4; ++d) {
            int j  = j0 + d;
            int pq = (i + j) & 1;          // parity owning column j of row i
            int q  = (il << 5) | (j >> 1);
            vv[d] = cls[oc * CLS_OC + pq * 64 + q];
        }
        *(f32x4*)(out + (((size_t)n * C_OUT + oc) * HH + i) * WW + j0) = vv;
    }
}

extern "C" void kernel_launch(void* const* d_in, const int* in_sizes, int n_in,
                              void* d_out, int out_size, void* d_ws, size_t ws_size,
                              hipStream_t stream) {
    const float* x = (const float*)d_in[0];
    const float* w = (const float*)d_in[1];
    float* out = (float*)d_out;
    (void)d_ws; (void)ws_size;

    aeg_mfma<<<256, 512, 0, stream>>>(x, w, out);
}